// Round 6
// baseline (163.821 us; speedup 1.0000x reference)
//
#include <hip/hip_runtime.h>
#include <math.h>

typedef __attribute__((ext_vector_type(8)))  short short8;     // 8 bf16 = 4 VGPRs
typedef __attribute__((ext_vector_type(16))) float floatx16;   // MFMA 32x32 acc

constexpr int NPTS   = 16384;             // P == G
constexpr int BLOCK  = 256;
constexpr int QPB    = 256;               // queries per block (8 tiles of 32)
constexpr int QBLKS  = NPTS / QPB;        // 64
constexpr int TSPLIT = 8;                 // target splits
constexpr int TCHUNK = NPTS / TSPLIT;     // 2048 targets per block sweep
constexpr int MTILES = TCHUNK / 32;       // 64 m-tiles per sweep
constexpr unsigned NB_DIR = QBLKS * TSPLIT;  // 512 blocks per direction

// bf16 round-to-nearest-even split helpers (values are finite, O(10))
__device__ __forceinline__ unsigned short f2bf(float f) {
    unsigned u = __float_as_uint(f);
    return (unsigned short)((u + 0x7FFFu + ((u >> 16) & 1u)) >> 16);
}
__device__ __forceinline__ float bf2f(unsigned short s) {
    return __uint_as_float(((unsigned)s) << 16);
}

// ---------------------------------------------------------------------------
// Setup: build split-bf16 MFMA packs (16 bf16 = 32 B per point per role).
// K-slot layout (sum over k of T[k]*Q[k] = t^2 + q^2 - 2 t.q = d^2):
//   coord c (slots 4c..4c+3): target [sh,sh,sl,sl] (s = -2*coord split),
//                             query  [qh,ql,qh,ql] (coord split)
//   slots 12,13: target [t2h,t2l], query [1,1]
//   slots 14,15: target [1,1],     query [q2h,q2l]
// Also init min arrays to +inf bits and tickets to 0 (ws re-poisoned per call).
// ---------------------------------------------------------------------------
__global__ __launch_bounds__(BLOCK) void setup_kernel(
    const float* __restrict__ pred, const float* __restrict__ gt,
    unsigned short* __restrict__ tpP, unsigned short* __restrict__ qpP,
    unsigned short* __restrict__ tpG, unsigned short* __restrict__ qpG,
    unsigned* __restrict__ minP, unsigned* __restrict__ minG,
    unsigned* __restrict__ tickets)
{
    const int i = blockIdx.x * BLOCK + threadIdx.x;
    const unsigned short ONE = 0x3F80;   // bf16(1.0)

    const float* src[2] = {pred, gt};
    unsigned short* tdst[2] = {tpP, tpG};
    unsigned short* qdst[2] = {qpP, qpG};

    #pragma unroll
    for (int cl = 0; cl < 2; ++cl) {
        float c0 = src[cl][3*i], c1 = src[cl][3*i+1], c2 = src[cl][3*i+2];
        float n2 = fmaf(c0, c0, fmaf(c1, c1, c2 * c2));
        float c[3] = {c0, c1, c2};
        __align__(16) unsigned short t[16], q[16];
        #pragma unroll
        for (int d = 0; d < 3; ++d) {
            float s = -2.0f * c[d];
            unsigned short sh = f2bf(s), sl = f2bf(s - bf2f(sh));
            t[4*d+0] = sh; t[4*d+1] = sh; t[4*d+2] = sl; t[4*d+3] = sl;
            unsigned short qh = f2bf(c[d]), ql = f2bf(c[d] - bf2f(qh));
            q[4*d+0] = qh; q[4*d+1] = ql; q[4*d+2] = qh; q[4*d+3] = ql;
        }
        unsigned short nh = f2bf(n2), nl = f2bf(n2 - bf2f(nh));
        t[12] = nh;  t[13] = nl;  t[14] = ONE; t[15] = ONE;
        q[12] = ONE; q[13] = ONE; q[14] = nh;  q[15] = nl;

        uint4* td = (uint4*)(tdst[cl] + (size_t)i * 16);
        uint4* qd = (uint4*)(qdst[cl] + (size_t)i * 16);
        td[0] = ((uint4*)t)[0]; td[1] = ((uint4*)t)[1];
        qd[0] = ((uint4*)q)[0]; qd[1] = ((uint4*)q)[1];
    }
    minP[i] = 0x7F800000u;   // +inf
    minG[i] = 0x7F800000u;
    if (i < 3) tickets[i] = 0u;
}

// min of 16 acc values (compiler folds to v_min3 chains)
__device__ __forceinline__ float tree16(floatx16 v) {
    float a = fminf(fminf(v[0],  v[1]),  fminf(v[2],  v[3]));
    float b = fminf(fminf(v[4],  v[5]),  fminf(v[6],  v[7]));
    float c = fminf(fminf(v[8],  v[9]),  fminf(v[10], v[11]));
    float d = fminf(fminf(v[12], v[13]), fminf(v[14], v[15]));
    return fminf(fminf(a, b), fminf(c, d));
}

// ---------------------------------------------------------------------------
// MFMA Chamfer. blockIdx = (query-block, target-split, direction).
// Wave holds 2 query B-frags in registers; streams target A-frags from
// global (L2-resident, coalesced 16 B/lane). D = A(targets) x B(queries)
// = full d^2 tile. Running min per lane uses col=lane&31 [m74/m101];
// min over 16 regs + shfl_xor(32) covers all 32 target rows.
// Tail: per-direction ticket -> last block reduces; second finisher writes out.
// ---------------------------------------------------------------------------
__global__ __launch_bounds__(BLOCK, 4) void chamfer_mfma_kernel(
    const unsigned short* __restrict__ tpP, const unsigned short* __restrict__ qpP,
    const unsigned short* __restrict__ tpG, const unsigned short* __restrict__ qpG,
    const float* __restrict__ wpred, const float* __restrict__ wgt,
    unsigned* __restrict__ minP, unsigned* __restrict__ minG,
    float* __restrict__ accum, unsigned* __restrict__ tickets,
    float* __restrict__ outp)
{
    const int dir = blockIdx.z;
    // dir 0: queries = pred, targets = gt  -> per-pred minima (minP)
    const short8* tp = (const short8*)((dir == 0) ? tpG : tpP);
    const short8* qp = (const short8*)((dir == 0) ? qpP : qpG);
    unsigned*   omin = (dir == 0) ? minP : minG;

    const int tid  = threadIdx.x;
    const int wave = tid >> 6;
    const int lane = tid & 63;
    const int l31  = lane & 31;
    const int h    = lane >> 5;          // K half: k = h*8 + j

    const int qbase = blockIdx.x * QPB;
    const int n0 = qbase + wave * 64;    // wave's two query tiles
    const int n1 = n0 + 32;
    const int tb = blockIdx.y * TCHUNK;

    // B-frags (queries) — register resident for the whole sweep
    const short8 bf0 = qp[(size_t)(n0 + l31) * 2 + h];
    const short8 bf1 = qp[(size_t)(n1 + l31) * 2 + h];

    const floatx16 zero = {0.0f};
    float mn0 = INFINITY, mn1 = INFINITY;

    #pragma unroll 2
    for (int mt = 0; mt < MTILES; ++mt) {
        const short8 af = tp[(size_t)(tb + mt * 32 + l31) * 2 + h];
        floatx16 a0 = __builtin_amdgcn_mfma_f32_32x32x16_bf16(af, bf0, zero, 0, 0, 0);
        floatx16 a1 = __builtin_amdgcn_mfma_f32_32x32x16_bf16(af, bf1, zero, 0, 0, 0);
        mn0 = fminf(mn0, tree16(a0));
        mn1 = fminf(mn1, tree16(a1));
    }

    // combine the two row-halves (lane>>5), then one atomicMin per query
    mn0 = fminf(mn0, __shfl_xor(mn0, 32));
    mn1 = fminf(mn1, __shfl_xor(mn1, 32));
    if (h == 0) {
        atomicMin(&omin[n0 + l31], __float_as_uint(fmaxf(mn0, 0.0f)));
        atomicMin(&omin[n1 + l31], __float_as_uint(fmaxf(mn1, 0.0f)));
    }

    // ---- per-direction completion ticket --------------------------------
    __threadfence();
    __syncthreads();
    __shared__ unsigned last;
    if (tid == 0) last = atomicAdd(&tickets[dir], 1u);
    __syncthreads();

    if (last == NB_DIR - 1) {
        const float* w = (dir == 0) ? wpred : wgt;
        float num = 0.0f, den = 0.0f;
        for (int i = tid; i < NPTS; i += BLOCK) {
            unsigned mb = atomicOr(&omin[i], 0u);   // coherent RMW read
            float wv = w[i];
            num = fmaf(wv, __uint_as_float(mb), num);
            den += wv;
        }
        for (int off = 32; off > 0; off >>= 1) {
            num += __shfl_down(num, off);
            den += __shfl_down(den, off);
        }
        __shared__ float rn[BLOCK / 64], rd[BLOCK / 64];
        int wid = tid >> 6, ln = tid & 63;
        if (ln == 0) { rn[wid] = num; rd[wid] = den; }
        __syncthreads();
        if (tid == 0) {
            float tn = rn[0] + rn[1] + rn[2] + rn[3];
            float td = rd[0] + rd[1] + rd[2] + rd[3];
            atomicExch(&accum[2*dir],     tn);
            atomicExch(&accum[2*dir + 1], td);
            __threadfence();
            unsigned o = atomicAdd(&tickets[2], 1u);
            if (o == 1) {                           // second finisher
                unsigned* ua = (unsigned*)accum;
                float n0v = __uint_as_float(atomicOr(&ua[0], 0u));
                float d0v = __uint_as_float(atomicOr(&ua[1], 0u));
                float n1v = __uint_as_float(atomicOr(&ua[2], 0u));
                float d1v = __uint_as_float(atomicOr(&ua[3], 0u));
                outp[0] = n0v / fmaxf(d0v, 1e-9f) + n1v / fmaxf(d1v, 1e-9f);
            }
        }
    }
}

// ---------------------------------------------------------------------------
extern "C" void kernel_launch(void* const* d_in, const int* in_sizes, int n_in,
                              void* d_out, int out_size, void* d_ws, size_t ws_size,
                              hipStream_t stream)
{
    const float* pred  = (const float*)d_in[0];   // (P,3)
    const float* gt    = (const float*)d_in[1];   // (G,3)
    const float* wpred = (const float*)d_in[2];   // (P,)
    const float* wgt   = (const float*)d_in[3];   // (G,)
    float* out = (float*)d_out;

    // ws: tpP | qpP | tpG | qpG (4 x 512 KB) | minP | minG | accum[4] | tickets[3]
    unsigned short* tpP = (unsigned short*)d_ws;
    unsigned short* qpP = tpP + (size_t)NPTS * 16;
    unsigned short* tpG = qpP + (size_t)NPTS * 16;
    unsigned short* qpG = tpG + (size_t)NPTS * 16;
    unsigned* minP    = (unsigned*)(qpG + (size_t)NPTS * 16);
    unsigned* minG    = minP + NPTS;
    float*    accum   = (float*)(minG + NPTS);
    unsigned* tickets = (unsigned*)(accum + 4);

    setup_kernel<<<NPTS / BLOCK, BLOCK, 0, stream>>>(
        pred, gt, tpP, qpP, tpG, qpG, minP, minG, tickets);

    dim3 grid(QBLKS, TSPLIT, 2);   // 64 x 8 x 2 = 1024 blocks
    chamfer_mfma_kernel<<<grid, BLOCK, 0, stream>>>(
        tpP, qpP, tpG, qpG, wpred, wgt, minP, minG, accum, tickets, out);
}

// Round 7
// 158.931 us; speedup vs baseline: 1.0308x; 1.0308x over previous
//
#include <hip/hip_runtime.h>
#include <math.h>

typedef __attribute__((ext_vector_type(8)))  short short8;     // 8 bf16 = 4 VGPRs
typedef __attribute__((ext_vector_type(16))) float floatx16;   // MFMA 32x32 acc

constexpr int NPTS   = 16384;             // P == G
constexpr int BLOCK  = 256;
constexpr int QPB    = 256;               // queries per block (4 waves x 2 tiles)
constexpr int QBLKS  = NPTS / QPB;        // 64
constexpr int TSPLIT = 8;                 // target splits
constexpr int TCHUNK = NPTS / TSPLIT;     // 2048 targets per block sweep
constexpr int STAGE  = 512;               // targets per LDS round (16 KB)
constexpr int ROUNDS = TCHUNK / STAGE;    // 4
constexpr int STEPS  = STAGE / 64;        // 8 (2 target tiles per step)
constexpr unsigned NB_DIR = QBLKS * TSPLIT;  // 512 blocks per direction

// bf16 round-to-nearest-even split helpers
__device__ __forceinline__ unsigned short f2bf(float f) {
    unsigned u = __float_as_uint(f);
    return (unsigned short)((u + 0x7FFFu + ((u >> 16) & 1u)) >> 16);
}
__device__ __forceinline__ float bf2f(unsigned short s) {
    return __uint_as_float(((unsigned)s) << 16);
}

// ---------------------------------------------------------------------------
// Setup: build split-bf16 MFMA packs (16 bf16 = 32 B per point per role).
// K-slot layout (sum_k T[k]*Q[k] = t^2 + q^2 - 2 t.q = d^2):
//   coord c (slots 4c..4c+3): target [sh,sh,sl,sl] (s = -2*coord, hi/lo split)
//                             query  [qh,ql,qh,ql] (coord hi/lo split)
//   slots 12,13: target [t2h,t2l], query [1,1]
//   slots 14,15: target [1,1],     query [q2h,q2l]
// Init min arrays to +inf bits, tickets to 0 (ws re-poisoned every call).
// ---------------------------------------------------------------------------
__global__ __launch_bounds__(BLOCK) void setup_kernel(
    const float* __restrict__ pred, const float* __restrict__ gt,
    unsigned short* __restrict__ tpP, unsigned short* __restrict__ qpP,
    unsigned short* __restrict__ tpG, unsigned short* __restrict__ qpG,
    unsigned* __restrict__ minP, unsigned* __restrict__ minG,
    unsigned* __restrict__ tickets)
{
    const int i = blockIdx.x * BLOCK + threadIdx.x;
    const unsigned short ONE = 0x3F80;   // bf16(1.0)

    const float* src[2] = {pred, gt};
    unsigned short* tdst[2] = {tpP, tpG};
    unsigned short* qdst[2] = {qpP, qpG};

    #pragma unroll
    for (int cl = 0; cl < 2; ++cl) {
        float c0 = src[cl][3*i], c1 = src[cl][3*i+1], c2 = src[cl][3*i+2];
        float n2 = fmaf(c0, c0, fmaf(c1, c1, c2 * c2));
        float c[3] = {c0, c1, c2};
        __align__(16) unsigned short t[16], q[16];
        #pragma unroll
        for (int d = 0; d < 3; ++d) {
            float s = -2.0f * c[d];
            unsigned short sh = f2bf(s), sl = f2bf(s - bf2f(sh));
            t[4*d+0] = sh; t[4*d+1] = sh; t[4*d+2] = sl; t[4*d+3] = sl;
            unsigned short qh = f2bf(c[d]), ql = f2bf(c[d] - bf2f(qh));
            q[4*d+0] = qh; q[4*d+1] = ql; q[4*d+2] = qh; q[4*d+3] = ql;
        }
        unsigned short nh = f2bf(n2), nl = f2bf(n2 - bf2f(nh));
        t[12] = nh;  t[13] = nl;  t[14] = ONE; t[15] = ONE;
        q[12] = ONE; q[13] = ONE; q[14] = nh;  q[15] = nl;

        uint4* td = (uint4*)(tdst[cl] + (size_t)i * 16);
        uint4* qd = (uint4*)(qdst[cl] + (size_t)i * 16);
        td[0] = ((uint4*)t)[0]; td[1] = ((uint4*)t)[1];
        qd[0] = ((uint4*)q)[0]; qd[1] = ((uint4*)q)[1];
    }
    minP[i] = 0x7F800000u;   // +inf
    minG[i] = 0x7F800000u;
    if (i < 3) tickets[i] = 0u;
}

// final min of the 16 acc values (folds to v_min3 chains)
__device__ __forceinline__ float tree16(floatx16 v) {
    float a = fminf(fminf(v[0],  v[1]),  fminf(v[2],  v[3]));
    float b = fminf(fminf(v[4],  v[5]),  fminf(v[6],  v[7]));
    float c = fminf(fminf(v[8],  v[9]),  fminf(v[10], v[11]));
    float d = fminf(fminf(v[12], v[13]), fminf(v[14], v[15]));
    return fminf(fminf(a, b), fminf(c, d));
}

// ---------------------------------------------------------------------------
// MFMA Chamfer, latency-fixed:
//  - targets staged in LDS (16 KB rounds), shared by the block's 4 waves
//  - per step: 2 target tiles x 2 query frags = 4 MFMAs, then elementwise
//    min3 into two running floatx16 accumulators (16 independent dep chains,
//    8 VALU insts per MFMA; tree16 runs ONCE at the end)
//  - C/D reg->row map is tile-invariant, so elementwise min across tiles is
//    exactly min over targets per (lane,reg) slot.
// ---------------------------------------------------------------------------
__global__ __launch_bounds__(BLOCK, 4) void chamfer_mfma_kernel(
    const unsigned short* __restrict__ tpP, const unsigned short* __restrict__ qpP,
    const unsigned short* __restrict__ tpG, const unsigned short* __restrict__ qpG,
    const float* __restrict__ wpred, const float* __restrict__ wgt,
    unsigned* __restrict__ minP, unsigned* __restrict__ minG,
    float* __restrict__ accum, unsigned* __restrict__ tickets,
    float* __restrict__ outp)
{
    const int dir = blockIdx.z;
    // dir 0: queries = pred, targets = gt -> per-pred minima (minP)
    const uint4*  tp = (const uint4*)((dir == 0) ? tpG : tpP);   // 2 uint4/point
    const short8* qp = (const short8*)((dir == 0) ? qpP : qpG);
    unsigned*   omin = (dir == 0) ? minP : minG;

    __shared__ uint4 sT[STAGE * 2];   // 16 KB, tile-major: tile*64 + h*32 + lane

    const int tid  = threadIdx.x;
    const int wave = tid >> 6;
    const int lane = tid & 63;
    const int l31  = lane & 31;
    const int h    = lane >> 5;          // K half: k = h*8 + j

    const int n0 = blockIdx.x * QPB + wave * 64;   // wave's two query tiles
    const int n1 = n0 + 32;
    const int tb = blockIdx.y * TCHUNK;

    // B-frags (queries) — register resident for the whole sweep
    const short8 bf0 = qp[(size_t)(n0 + l31) * 2 + h];
    const short8 bf1 = qp[(size_t)(n1 + l31) * 2 + h];

    const floatx16 zero = {0.0f};
    floatx16 mn0, mn1;
    #pragma unroll
    for (int i = 0; i < 16; ++i) { mn0[i] = INFINITY; mn1[i] = INFINITY; }

    for (int r = 0; r < ROUNDS; ++r) {
        // ---- stage 512 targets (16 KB) cooperatively, tile-transposed ----
        {
            const int base = (tb + r * STAGE) * 2;    // uint4 index in tp
            #pragma unroll
            for (int j = 0; j < 4; ++j) {
                int f = j * BLOCK + tid;              // 0..1023, coalesced
                uint4 v = tp[base + f];
                int p = f >> 1, hh = f & 1;
                sT[(p >> 5) * 64 + hh * 32 + (p & 31)] = v;
            }
        }
        __syncthreads();

        #pragma unroll 2
        for (int s = 0; s < STEPS; ++s) {
            const short8 af0 = ((const short8*)sT)[(2*s)   * 64 + h * 32 + l31];
            const short8 af1 = ((const short8*)sT)[(2*s+1) * 64 + h * 32 + l31];
            floatx16 d0 = __builtin_amdgcn_mfma_f32_32x32x16_bf16(af0, bf0, zero, 0, 0, 0);
            floatx16 e0 = __builtin_amdgcn_mfma_f32_32x32x16_bf16(af1, bf0, zero, 0, 0, 0);
            #pragma unroll
            for (int i = 0; i < 16; ++i)
                mn0[i] = fminf(fminf(mn0[i], d0[i]), e0[i]);   // v_min3
            floatx16 d1 = __builtin_amdgcn_mfma_f32_32x32x16_bf16(af0, bf1, zero, 0, 0, 0);
            floatx16 e1 = __builtin_amdgcn_mfma_f32_32x32x16_bf16(af1, bf1, zero, 0, 0, 0);
            #pragma unroll
            for (int i = 0; i < 16; ++i)
                mn1[i] = fminf(fminf(mn1[i], d1[i]), e1[i]);
        }
        __syncthreads();
    }

    // final per-query min: 16 regs -> 1, then the other row-half via shfl
    float m0 = tree16(mn0);
    float m1 = tree16(mn1);
    m0 = fminf(m0, __shfl_xor(m0, 32));
    m1 = fminf(m1, __shfl_xor(m1, 32));
    if (h == 0) {
        atomicMin(&omin[n0 + l31], __float_as_uint(fmaxf(m0, 0.0f)));
        atomicMin(&omin[n1 + l31], __float_as_uint(fmaxf(m1, 0.0f)));
    }

    // ---- per-direction completion ticket --------------------------------
    __threadfence();
    __syncthreads();
    __shared__ unsigned last;
    if (tid == 0) last = atomicAdd(&tickets[dir], 1u);
    __syncthreads();

    if (last == NB_DIR - 1) {
        const float* w = (dir == 0) ? wpred : wgt;
        float num = 0.0f, den = 0.0f;
        for (int i = tid; i < NPTS; i += BLOCK) {
            unsigned mb = atomicOr(&omin[i], 0u);   // coherent RMW read
            float wv = w[i];
            num = fmaf(wv, __uint_as_float(mb), num);
            den += wv;
        }
        for (int off = 32; off > 0; off >>= 1) {
            num += __shfl_down(num, off);
            den += __shfl_down(den, off);
        }
        __shared__ float rn[BLOCK / 64], rd[BLOCK / 64];
        int wid = tid >> 6, ln = tid & 63;
        if (ln == 0) { rn[wid] = num; rd[wid] = den; }
        __syncthreads();
        if (tid == 0) {
            float tn = rn[0] + rn[1] + rn[2] + rn[3];
            float td = rd[0] + rd[1] + rd[2] + rd[3];
            atomicExch(&accum[2*dir],     tn);
            atomicExch(&accum[2*dir + 1], td);
            __threadfence();
            unsigned o = atomicAdd(&tickets[2], 1u);
            if (o == 1) {                           // second finisher
                unsigned* ua = (unsigned*)accum;
                float n0v = __uint_as_float(atomicOr(&ua[0], 0u));
                float d0v = __uint_as_float(atomicOr(&ua[1], 0u));
                float n1v = __uint_as_float(atomicOr(&ua[2], 0u));
                float d1v = __uint_as_float(atomicOr(&ua[3], 0u));
                outp[0] = n0v / fmaxf(d0v, 1e-9f) + n1v / fmaxf(d1v, 1e-9f);
            }
        }
    }
}

// ---------------------------------------------------------------------------
extern "C" void kernel_launch(void* const* d_in, const int* in_sizes, int n_in,
                              void* d_out, int out_size, void* d_ws, size_t ws_size,
                              hipStream_t stream)
{
    const float* pred  = (const float*)d_in[0];   // (P,3)
    const float* gt    = (const float*)d_in[1];   // (G,3)
    const float* wpred = (const float*)d_in[2];   // (P,)
    const float* wgt   = (const float*)d_in[3];   // (G,)
    float* out = (float*)d_out;

    // ws: tpP | qpP | tpG | qpG (4 x 512 KB) | minP | minG | accum[4] | tickets[3]
    unsigned short* tpP = (unsigned short*)d_ws;
    unsigned short* qpP = tpP + (size_t)NPTS * 16;
    unsigned short* tpG = qpP + (size_t)NPTS * 16;
    unsigned short* qpG = tpG + (size_t)NPTS * 16;
    unsigned* minP    = (unsigned*)(qpG + (size_t)NPTS * 16);
    unsigned* minG    = minP + NPTS;
    float*    accum   = (float*)(minG + NPTS);
    unsigned* tickets = (unsigned*)(accum + 4);

    setup_kernel<<<NPTS / BLOCK, BLOCK, 0, stream>>>(
        pred, gt, tpP, qpP, tpG, qpG, minP, minG, tickets);

    dim3 grid(QBLKS, TSPLIT, 2);   // 64 x 8 x 2 = 1024 blocks
    chamfer_mfma_kernel<<<grid, BLOCK, 0, stream>>>(
        tpP, qpP, tpG, qpG, wpred, wgt, minP, minG, accum, tickets, out);
}